// Round 4
// baseline (571.275 us; speedup 1.0000x reference)
//
#include <hip/hip_runtime.h>
#include <hip/hip_bf16.h>

#define THREADS 256
#define HP 136     // padded LDS row stride (shorts) for h rows
#define FEXP 20    // fex row stride in f32 (16 + 4 pad, keeps 16B alignment)

typedef float f32x4 __attribute__((ext_vector_type(4)));
typedef short s16x8 __attribute__((ext_vector_type(8)));

static __device__ __forceinline__ short f2b(float x) {
    return __builtin_bit_cast(short, __float2bfloat16(x));
}
static __device__ __forceinline__ float b2f(short u) {
    unsigned int v = ((unsigned int)(unsigned short)u) << 16;
    return __builtin_bit_cast(float, v);
}
static __device__ __forceinline__ void split8(const f32x4 a, const f32x4 b, s16x8& hi, s16x8& lo) {
    #pragma unroll
    for (int j = 0; j < 4; ++j) {
        short h0 = f2b(a[j]); hi[j]   = h0; lo[j]   = f2b(a[j] - b2f(h0));
        short h1 = f2b(b[j]); hi[j+4] = h1; lo[j+4] = f2b(b[j] - b2f(h1));
    }
}
static __device__ __forceinline__ s16x8 cvt8(const f32x4 a, const f32x4 b) {
    s16x8 r;
    r[0]=f2b(a[0]); r[1]=f2b(a[1]); r[2]=f2b(a[2]); r[3]=f2b(a[3]);
    r[4]=f2b(b[0]); r[5]=f2b(b[1]); r[6]=f2b(b[2]); r[7]=f2b(b[3]);
    return r;
}
static __device__ __forceinline__ float sigm(float x) { return 1.0f / (1.0f + __expf(-x)); }

#define MFMA16(A,B,C) __builtin_amdgcn_mfma_f32_16x16x32_bf16((A),(B),(C),0,0,0)

// ---- pre-pass: split Wf1/Wf2 into hi/lo bf16 image + W2 -> bf16 ----
// ws layout (shorts): [wv][cp][plane][row][k32] = 2*32*2*128*32 = 524288 shorts (1 MB)
//                     then W2 bf16 [128][128]   = 16384 shorts (32 KB)
__global__ __launch_bounds__(256) void itemfusing_prep(
    const float* __restrict__ Wf1, const float* __restrict__ Wf2,
    const float* __restrict__ W2, short* __restrict__ wsp)
{
    const int t = blockIdx.x * 256 + threadIdx.x;
    if (t < 65536) {
        const int idx = t * 8;
        const int k0 = idx & 31;
        const int r  = (idx >> 5) & 127;
        const int p  = (idx >> 12) & 1;
        const int cp = (idx >> 13) & 31;
        const int wv = idx >> 18;
        const float* src = (wv ? Wf2 : Wf1) + (size_t)r * 1024 + cp * 32 + k0;
        f32x4 a = *(const f32x4*)src, b = *(const f32x4*)(src + 4);
        s16x8 hi, lo; split8(a, b, hi, lo);
        *(s16x8*)(wsp + idx) = p ? lo : hi;
    } else {
        const int t2 = t - 65536;
        if (t2 < 2048) {
            const int idx = t2 * 8;
            const float* src = W2 + idx;
            *(s16x8*)(wsp + 524288 + idx) = cvt8(*(const f32x4*)src, *(const f32x4*)(src + 4));
        }
    }
}

// Paired-wave main: wave (pr,fz) computes weight-fz GEMM for session pr (32 rows, K=1024),
// B-frags direct from L2-resident pre-split image -> registers. No barriers in phase 1.
template<bool PRE>
__global__ __launch_bounds__(THREADS, 2) void itemfusing_main(
    const float* __restrict__ inter, const float* __restrict__ intra,
    const float* __restrict__ Wf1, const float* __restrict__ bf1,
    const float* __restrict__ Wf2, const float* __restrict__ bf2,
    const float* __restrict__ W1,  const float* __restrict__ b1,
    const float* __restrict__ W2,  const float* __restrict__ b2,
    const float* __restrict__ qw,  const float* __restrict__ qb,
    const float* __restrict__ W3,  const float* __restrict__ b3,
    const short* __restrict__ wsp, const short* __restrict__ w2b,
    float* __restrict__ out)
{
    __shared__ float fex[2][2][128][FEXP];  // [pr][srcwave][n][row16] : 40960 B
    __shared__ short hbuf[2][32][HP];       // 17408 B
    __shared__ float vnb [2][128];          // 1024 B
    __shared__ float w1vb[2][128];          // 1024 B
    __shared__ float sglp[2][2][128];       // 2048 B  -> total 62464 B => 2 blocks/CU

    const int tid = threadIdx.x;
    const int l   = tid & 63;
    const int l15 = l & 15;
    const int kg  = (l >> 4) & 3;
    const int w   = tid >> 6;
    const int pr  = w >> 1;      // session slot 0..1
    const int fz  = w & 1;       // 0: f1 (inter,Wf1)  1: f2 (intra,Wf2)
    const int sess = blockIdx.x * 2 + pr;

    const float* Aemb = (fz ? intra : inter) + ((size_t)(sess * 32 + l15) * 1024 + kg * 8);
    const short* bimg = PRE ? (wsp + fz * 262144 + l15 * 32 + kg * 8) : nullptr;
    const float* wsrc = PRE ? nullptr
                            : ((fz ? Wf2 : Wf1) + (size_t)l15 * 1024 + kg * 8);

    f32x4 acc0[8], acc1[8];   // [nt] for rows mt=0 / mt=1
    #pragma unroll
    for (int nt = 0; nt < 8; ++nt) {
        acc0[nt] = f32x4{0.f, 0.f, 0.f, 0.f};
        acc1[nt] = f32x4{0.f, 0.f, 0.f, 0.f};
    }

    s16x8 bbA[16], bbB[16];   // B-frag double buffer: [nt*2 + plane]
    f32x4 ra[4], rn[4];       // A raw double buffer: [mt*2 + half]

#define BLOAD(DST, CP) do {                                                                  \
    if constexpr (PRE) {                                                                     \
        _Pragma("unroll")                                                                    \
        for (int i_ = 0; i_ < 16; ++i_)                                                      \
            DST[i_] = *(const s16x8*)(bimg + (size_t)(CP) * 8192 + (i_ & 1) * 4096           \
                                      + (i_ >> 1) * 512);                                    \
    } else {                                                                                 \
        _Pragma("unroll")                                                                    \
        for (int nt_ = 0; nt_ < 8; ++nt_) {                                                  \
            const float* p_ = wsrc + (size_t)nt_ * 16 * 1024 + (CP) * 32;                    \
            split8(*(const f32x4*)p_, *(const f32x4*)(p_ + 4),                               \
                   DST[nt_ * 2], DST[nt_ * 2 + 1]);                                          \
        }                                                                                    \
    } } while (0)

#define ALOAD(DST, CP) do {                                                                  \
    const float* p_ = Aemb + (CP) * 32;                                                      \
    DST[0] = *(const f32x4*)p_;  DST[1] = *(const f32x4*)(p_ + 4);                           \
    const float* q_ = p_ + (size_t)16 * 1024;                                                \
    DST[2] = *(const f32x4*)q_;  DST[3] = *(const f32x4*)(q_ + 4); } while (0)

#define COMPUTE(BSET, ASET) do {                                                             \
    s16x8 ah0_, al0_, ah1_, al1_;                                                            \
    split8(ASET[0], ASET[1], ah0_, al0_);                                                    \
    split8(ASET[2], ASET[3], ah1_, al1_);                                                    \
    _Pragma("unroll")                                                                        \
    for (int nt_ = 0; nt_ < 8; ++nt_) {                                                      \
        s16x8 bh_ = BSET[nt_ * 2], bl_ = BSET[nt_ * 2 + 1];                                  \
        acc0[nt_] = MFMA16(ah0_, bh_, acc0[nt_]);                                            \
        acc1[nt_] = MFMA16(ah1_, bh_, acc1[nt_]);                                            \
        acc0[nt_] = MFMA16(al0_, bh_, acc0[nt_]);                                            \
        acc1[nt_] = MFMA16(al1_, bh_, acc1[nt_]);                                            \
        acc0[nt_] = MFMA16(ah0_, bl_, acc0[nt_]);                                            \
        acc1[nt_] = MFMA16(ah1_, bl_, acc1[nt_]);                                            \
    } } while (0)

    // ---------------- phase 1: 32 K-chunks, no barriers ----------------
    BLOAD(bbA, 0); ALOAD(ra, 0);
    #pragma unroll 1
    for (int c2 = 0; c2 < 16; ++c2) {
        const int cpB = c2 * 2 + 1;
        BLOAD(bbB, cpB); ALOAD(rn, cpB);
        COMPUTE(bbA, ra);
        if (c2 < 15) { BLOAD(bbA, cpB + 1); ALOAD(ra, cpB + 1); }
        COMPUTE(bbB, rn);
    }
#undef BLOAD
#undef ALOAD
#undef COMPUTE

    // ---------------- exchange: give other wave its missing weight half -----------
    if (fz == 0) {
        #pragma unroll
        for (int nt = 0; nt < 8; ++nt)
            *(f32x4*)&fex[pr][0][nt * 16 + l15][kg * 4] = acc1[nt];  // f1 rows 16-31
    } else {
        #pragma unroll
        for (int nt = 0; nt < 8; ++nt)
            *(f32x4*)&fex[pr][1][nt * 16 + l15][kg * 4] = acc0[nt];  // f2 rows 0-15
    }
    __syncthreads();   // B1

    // ---------------- gate: h for own 16 rows (row = fz*16 + kg*4 + rj) -----------
    f32x4 hreg[8];
    #pragma unroll
    for (int nt = 0; nt < 8; ++nt) {
        const int n = nt * 16 + l15;
        f32x4 oth = *(const f32x4*)&fex[pr][1 - fz][n][kg * 4];
        f32x4 own = fz ? acc1[nt] : acc0[nt];   // wave-uniform select
        const float bb1 = bf1[n], bb2 = bf2[n];
        #pragma unroll
        for (int rj = 0; rj < 4; ++rj) {
            float x1 = (fz ? oth[rj] : own[rj]) + bb1;
            float x2 = (fz ? own[rj] : oth[rj]) + bb2;
            float g  = sigm(x1 + x2);
            hreg[nt][rj] = x2 + g * (x1 - x2);
        }
    }

    // v_n (session row 31 = fz1 wave, kg=3, rj=3) + h rows -> LDS
    if (fz == 1 && kg == 3) {
        #pragma unroll
        for (int nt = 0; nt < 8; ++nt) vnb[pr][nt * 16 + l15] = hreg[nt][3];
    }
    #pragma unroll
    for (int nt = 0; nt < 8; ++nt)
        #pragma unroll
        for (int rj = 0; rj < 4; ++rj)
            hbuf[pr][fz * 16 + kg * 4 + rj][nt * 16 + l15] = f2b(hreg[nt][rj]);
    __syncthreads();   // B2: vn + hbuf visible

    // ---------------- w1v = W1 @ v_n + b1 (64 outputs per wave) -------------------
    {
        const int n = fz * 64 + l;
        const float* w1r = W1 + (size_t)n * 128;
        float a = b1[n];
        #pragma unroll
        for (int kk = 0; kk < 128; kk += 4) {
            f32x4 vv = *(const f32x4*)&vnb[pr][kk];
            f32x4 u0 = *(const f32x4*)(w1r + kk);
            #pragma unroll
            for (int j = 0; j < 4; ++j) a += u0[j] * vv[j];
        }
        w1vb[pr][n] = a;
    }

    // ---------------- w2h = h @ W2^T (MFMA, own 16 rows) --------------------------
    f32x4 aw[8];
    #pragma unroll
    for (int nt = 0; nt < 8; ++nt) aw[nt] = f32x4{0.f, 0.f, 0.f, 0.f};
    #pragma unroll
    for (int ks = 0; ks < 4; ++ks) {
        const int kl = ks * 32 + kg * 8;
        s16x8 ah = *(const s16x8*)&hbuf[pr][fz * 16 + l15][kl];
        #pragma unroll
        for (int nt = 0; nt < 8; ++nt) {
            s16x8 bw;
            if constexpr (PRE) {
                bw = *(const s16x8*)&w2b[(size_t)(nt * 16 + l15) * 128 + kl];
            } else {
                const float* wp = W2 + (size_t)(nt * 16 + l15) * 128 + kl;
                bw = cvt8(*(const f32x4*)wp, *(const f32x4*)(wp + 4));
            }
            aw[nt] = MFMA16(ah, bw, aw[nt]);
        }
    }
    __syncthreads();   // B3: w1vb visible (written above by both waves of pair)

    // ---------------- alpha rows (own 16 rows, wave-local) ------------------------
    float prt[4] = {0.f, 0.f, 0.f, 0.f};
    #pragma unroll
    for (int nt = 0; nt < 8; ++nt) {
        const int n = nt * 16 + l15;
        const float qn = qw[n], wv_ = w1vb[pr][n], bb = b2[n];
        #pragma unroll
        for (int rj = 0; rj < 4; ++rj)
            prt[rj] += qn * sigm(wv_ + aw[nt][rj] + bb);
    }
    const float qbias = qb[0];
    #pragma unroll
    for (int rj = 0; rj < 4; ++rj) {
        float v = prt[rj];
        v += __shfl_xor(v, 1); v += __shfl_xor(v, 2);
        v += __shfl_xor(v, 4); v += __shfl_xor(v, 8);
        prt[rj] = v + qbias;          // alpha for row fz*16 + kg*4 + rj
    }

    // ---------------- s_g partial over own 16 rows --------------------------------
    #pragma unroll
    for (int nt = 0; nt < 8; ++nt) {
        float sgv = 0.f;
        #pragma unroll
        for (int rj = 0; rj < 4; ++rj) sgv += prt[rj] * hreg[nt][rj];
        sgv += __shfl_xor(sgv, 16);
        sgv += __shfl_xor(sgv, 32);
        if (l < 16) sglp[pr][fz][nt * 16 + l15] = sgv;
    }
    __syncthreads();   // B4

    // ---------------- out = W3 @ [v_n ; s_g] + b3 ---------------------------------
    {
        const int n = fz * 64 + l;
        const float* w3r = W3 + (size_t)n * 256;
        float o = b3[n];
        #pragma unroll
        for (int kk = 0; kk < 128; kk += 4) {
            f32x4 vv = *(const f32x4*)&vnb[pr][kk];
            f32x4 s0 = *(const f32x4*)&sglp[pr][0][kk];
            f32x4 s1 = *(const f32x4*)&sglp[pr][1][kk];
            f32x4 a0 = *(const f32x4*)(w3r + kk);
            f32x4 c0 = *(const f32x4*)(w3r + 128 + kk);
            #pragma unroll
            for (int j = 0; j < 4; ++j)
                o += a0[j] * vv[j] + c0[j] * (s0[j] + s1[j]);
        }
        out[(size_t)sess * 128 + n] = o;
    }
}

extern "C" void kernel_launch(void* const* d_in, const int* in_sizes, int n_in,
                              void* d_out, int out_size, void* d_ws, size_t ws_size,
                              hipStream_t stream) {
    (void)n_in; (void)out_size;
    const float* inter = (const float*)d_in[0];
    const float* intra = (const float*)d_in[1];
    const float* Wf1   = (const float*)d_in[3];
    const float* bf1   = (const float*)d_in[4];
    const float* Wf2   = (const float*)d_in[5];
    const float* bf2   = (const float*)d_in[6];
    const float* W1    = (const float*)d_in[7];
    const float* b1    = (const float*)d_in[8];
    const float* W2    = (const float*)d_in[9];
    const float* b2    = (const float*)d_in[10];
    const float* qw    = (const float*)d_in[11];
    const float* qb    = (const float*)d_in[12];
    const float* W3    = (const float*)d_in[13];
    const float* b3    = (const float*)d_in[14];
    float* out = (float*)d_out;

    const int nsess   = in_sizes[2];     // 4096
    const int nblocks = nsess / 2;       // 2048

    const size_t WS_NEED = (size_t)(524288 + 16384) * sizeof(short);
    if (d_ws != nullptr && ws_size >= WS_NEED) {
        short* wsp = (short*)d_ws;
        itemfusing_prep<<<264, 256, 0, stream>>>(Wf1, Wf2, W2, wsp);
        itemfusing_main<true><<<nblocks, THREADS, 0, stream>>>(
            inter, intra, Wf1, bf1, Wf2, bf2, W1, b1, W2, b2, qw, qb, W3, b3,
            wsp, wsp + 524288, out);
    } else {
        itemfusing_main<false><<<nblocks, THREADS, 0, stream>>>(
            inter, intra, Wf1, bf1, Wf2, bf2, W1, b1, W2, b2, qw, qb, W3, b3,
            nullptr, nullptr, out);
    }
}

// Round 5
// 504.665 us; speedup vs baseline: 1.1320x; 1.1320x over previous
//
#include <hip/hip_runtime.h>
#include <hip/hip_bf16.h>

#define THREADS 256
#define HP 136     // padded LDS row stride (shorts) for h rows
#define FEXP 20    // fex row stride in f32 (16 + 4 pad, keeps 16B alignment)

typedef float f32x4 __attribute__((ext_vector_type(4)));
typedef short s16x8 __attribute__((ext_vector_type(8)));

static __device__ __forceinline__ short f2b(float x) {
    return __builtin_bit_cast(short, __float2bfloat16(x));
}
static __device__ __forceinline__ float b2f(short u) {
    unsigned int v = ((unsigned int)(unsigned short)u) << 16;
    return __builtin_bit_cast(float, v);
}
static __device__ __forceinline__ void split8(const f32x4 a, const f32x4 b, s16x8& hi, s16x8& lo) {
    #pragma unroll
    for (int j = 0; j < 4; ++j) {
        short h0 = f2b(a[j]); hi[j]   = h0; lo[j]   = f2b(a[j] - b2f(h0));
        short h1 = f2b(b[j]); hi[j+4] = h1; lo[j+4] = f2b(b[j] - b2f(h1));
    }
}
static __device__ __forceinline__ s16x8 cvt8(const f32x4 a, const f32x4 b) {
    s16x8 r;
    r[0]=f2b(a[0]); r[1]=f2b(a[1]); r[2]=f2b(a[2]); r[3]=f2b(a[3]);
    r[4]=f2b(b[0]); r[5]=f2b(b[1]); r[6]=f2b(b[2]); r[7]=f2b(b[3]);
    return r;
}
static __device__ __forceinline__ float sigm(float x) { return 1.0f / (1.0f + __expf(-x)); }

static __device__ __forceinline__ void gload16(const short* g, short* l3) {
    __builtin_amdgcn_global_load_lds((const __attribute__((address_space(1))) void*)g,
                                     (__attribute__((address_space(3))) void*)l3, 16, 0, 0);
}

#define MFMA16(A,B,C) __builtin_amdgcn_mfma_f32_16x16x32_bf16((A),(B),(C),0,0,0)

// Counted-vmcnt barrier: region data ready, without draining newer prefetch.
#define WAITBAR(N) do {                                             \
    asm volatile("s_waitcnt vmcnt(" #N ")" ::: "memory");           \
    __builtin_amdgcn_s_barrier();                                   \
    asm volatile("" ::: "memory"); } while (0)
// Buffer-release barrier: all ds_reads of the buffer retired first.
#define RELBAR() do {                                               \
    asm volatile("s_waitcnt lgkmcnt(0)" ::: "memory");              \
    __builtin_amdgcn_s_barrier();                                   \
    asm volatile("" ::: "memory"); } while (0)

// ---- pre-pass: build swizzled hi/lo weight image + W2 bf16 -------------------
// image (shorts): chunk cp (32 KB): [fz][plane][n][slot*8], slot = kg ^ ((n>>1)&3)
// total 32 chunks * 16384 = 524288 shorts (1 MB); then W2 bf16 [128][128] = 16384.
__global__ __launch_bounds__(256) void itemfusing_prep(
    const float* __restrict__ Wf1, const float* __restrict__ Wf2,
    const float* __restrict__ W2, short* __restrict__ wsp)
{
    const int t = blockIdx.x * 256 + threadIdx.x;
    if (t < 65536) {
        const int kg = t & 3;
        const int n  = (t >> 2) & 127;
        const int pl = (t >> 9) & 1;
        const int cp = (t >> 10) & 31;
        const int fz = (t >> 15) & 1;
        const float* src = (fz ? Wf2 : Wf1) + (size_t)n * 1024 + cp * 32 + kg * 8;
        s16x8 hi, lo; split8(*(const f32x4*)src, *(const f32x4*)(src + 4), hi, lo);
        const int slot = kg ^ ((n >> 1) & 3);
        *(s16x8*)(wsp + (size_t)cp * 16384 + fz * 8192 + pl * 4096 + n * 32 + slot * 8)
            = pl ? lo : hi;
    } else if (t < 65536 + 2048) {
        const int i = (t - 65536) * 8;
        const float* src = W2 + i;
        *(s16x8*)(wsp + 524288 + i) = cvt8(*(const f32x4*)src, *(const f32x4*)(src + 4));
    }
}

// ---- main: 4 waves = (session pr, weight fz); M=32/wave; K regions of 32 -----
__global__ __launch_bounds__(THREADS, 2) void itemfusing_main(
    const float* __restrict__ inter, const float* __restrict__ intra,
    const float* __restrict__ bf1, const float* __restrict__ bf2,
    const float* __restrict__ W1,  const float* __restrict__ b1,
    const float* __restrict__ b2,
    const float* __restrict__ qw,  const float* __restrict__ qb,
    const float* __restrict__ W3,  const float* __restrict__ b3,
    const short* __restrict__ gimg, const short* __restrict__ w2b,
    float* __restrict__ out)
{
    __shared__ union {
        short wimg[2][2][2][128][32];        // [buf][fz][plane][n][k] = 65536 B
        struct {
            float fex [2][2][128][FEXP];     // 40960 B
            short hbuf[2][32][HP];           // 17408 B
            float vnb [2][128];              // 1024 B
            float w1vb[2][128];              // 1024 B
            float sglp[2][2][128];           // 2048 B  (= 62464 total)
        } t;
    } u;                                     // static 65536 B -> 2 blocks/CU

    const int tid = threadIdx.x;
    const int l   = tid & 63;
    const int l15 = l & 15;
    const int kg  = l >> 4;
    const int w   = tid >> 6;
    const int pr  = w >> 1;      // session slot 0..1
    const int fz  = w & 1;       // 0: f1 (inter,Wf1)  1: f2 (intra,Wf2)
    const int sess = blockIdx.x * 2 + pr;
    const int slot8 = (kg ^ ((l15 >> 1) & 3)) * 8;

    const float* Aemb = (fz ? intra : inter) + ((size_t)(sess * 32 + l15) * 1024 + kg * 8);
    short* lbase = &u.wimg[0][0][0][0][0];

    f32x4 acc0[8], acc1[8];
    #pragma unroll
    for (int nt = 0; nt < 8; ++nt) {
        acc0[nt] = f32x4{0.f, 0.f, 0.f, 0.f};
        acc1[nt] = f32x4{0.f, 0.f, 0.f, 0.f};
    }

    f32x4 a0_0, a0_1, a0_2, a0_3;   // A set for even regions
    f32x4 a1_0, a1_1, a1_2, a1_3;   // A set for odd regions

#define ISSUE_B(CP, BUF) do {                                                   \
    _Pragma("unroll")                                                           \
    for (int i_ = 0; i_ < 8; ++i_)                                              \
        gload16(gimg + (size_t)(CP) * 16384 + (w * 8 + i_) * 512 + l * 8,       \
                lbase + (BUF) * 16384 + (w * 8 + i_) * 512);                    \
    } while (0)

#define ISSUE_A(SET, CP) do {                                                   \
    const float* p_ = Aemb + (CP) * 32;                                         \
    SET##_0 = *(const f32x4*)p_;  SET##_1 = *(const f32x4*)(p_ + 4);            \
    const float* q_ = p_ + (size_t)16 * 1024;                                   \
    SET##_2 = *(const f32x4*)q_;  SET##_3 = *(const f32x4*)(q_ + 4); } while (0)

#define COMPUTE(BUF, SET) do {                                                  \
    s16x8 ah0, al0, ah1, al1;                                                   \
    split8(SET##_0, SET##_1, ah0, al0);                                         \
    split8(SET##_2, SET##_3, ah1, al1);                                         \
    const short* fb_ = &u.wimg[BUF][0][0][0][0] + fz * 8192 + l15 * 32 + slot8; \
    _Pragma("unroll")                                                           \
    for (int nt_ = 0; nt_ < 8; ++nt_) {                                         \
        s16x8 bh_ = *(const s16x8*)(fb_ + nt_ * 512);                           \
        s16x8 bl_ = *(const s16x8*)(fb_ + 4096 + nt_ * 512);                    \
        acc0[nt_] = MFMA16(ah0, bh_, acc0[nt_]);                                \
        acc1[nt_] = MFMA16(ah1, bh_, acc1[nt_]);                                \
        acc0[nt_] = MFMA16(al0, bh_, acc0[nt_]);                                \
        acc1[nt_] = MFMA16(al1, bh_, acc1[nt_]);                                \
        acc0[nt_] = MFMA16(ah0, bl_, acc0[nt_]);                                \
        acc1[nt_] = MFMA16(ah1, bl_, acc1[nt_]);                                \
    } } while (0)

    // prologue: two regions in flight (12 vm-ops each: 8 B-gloads + 4 A-loads)
    ISSUE_B(0, 0); ISSUE_A(a0, 0);
    ISSUE_B(1, 1); ISSUE_A(a1, 1);

    #pragma unroll 1
    for (int c2 = 0; c2 < 16; ++c2) {
        const int c = 2 * c2;
        WAITBAR(12);                      // region c ready (c+1 stays in flight)
        COMPUTE(0, a0);
        RELBAR();                         // all waves done reading buf0
        if (c2 < 15) { ISSUE_B(c + 2, 0); ISSUE_A(a0, c + 2); }
        if (c2 < 15) { WAITBAR(12); } else { WAITBAR(0); }
        COMPUTE(1, a1);
        RELBAR();                         // all waves done reading buf1
        if (c2 < 15) { ISSUE_B(c + 3, 1); ISSUE_A(a1, c + 3); }
    }
#undef ISSUE_B
#undef ISSUE_A
#undef COMPUTE

    __syncthreads();   // phase 1 fully done; LDS becomes the tail union

    // ---------------- exchange: give paired wave its missing weight half ---------
    if (fz == 0) {
        #pragma unroll
        for (int nt = 0; nt < 8; ++nt)
            *(f32x4*)&u.t.fex[pr][0][nt * 16 + l15][kg * 4] = acc1[nt];  // f1 rows 16-31
    } else {
        #pragma unroll
        for (int nt = 0; nt < 8; ++nt)
            *(f32x4*)&u.t.fex[pr][1][nt * 16 + l15][kg * 4] = acc0[nt];  // f2 rows 0-15
    }
    __syncthreads();   // B1

    // ---------------- gate: h for own 16 rows (row = fz*16 + kg*4 + rj) ----------
    f32x4 hreg[8];
    #pragma unroll
    for (int nt = 0; nt < 8; ++nt) {
        const int n = nt * 16 + l15;
        f32x4 oth = *(const f32x4*)&u.t.fex[pr][1 - fz][n][kg * 4];
        f32x4 own = fz ? acc1[nt] : acc0[nt];
        const float bb1 = bf1[n], bb2 = bf2[n];
        #pragma unroll
        for (int rj = 0; rj < 4; ++rj) {
            float x1 = (fz ? oth[rj] : own[rj]) + bb1;
            float x2 = (fz ? own[rj] : oth[rj]) + bb2;
            float g  = sigm(x1 + x2);
            hreg[nt][rj] = x2 + g * (x1 - x2);
        }
    }

    // v_n (session row 31 = fz1 wave, kg=3, rj=3) + h rows -> LDS
    if (fz == 1 && kg == 3) {
        #pragma unroll
        for (int nt = 0; nt < 8; ++nt) u.t.vnb[pr][nt * 16 + l15] = hreg[nt][3];
    }
    #pragma unroll
    for (int nt = 0; nt < 8; ++nt)
        #pragma unroll
        for (int rj = 0; rj < 4; ++rj)
            u.t.hbuf[pr][fz * 16 + kg * 4 + rj][nt * 16 + l15] = f2b(hreg[nt][rj]);
    __syncthreads();   // B2: vn + hbuf visible

    // ---------------- w1v = W1 @ v_n + b1 (64 outputs per wave) ------------------
    {
        const int n = fz * 64 + l;
        const float* w1r = W1 + (size_t)n * 128;
        float a = b1[n];
        #pragma unroll
        for (int kk = 0; kk < 128; kk += 4) {
            f32x4 vv = *(const f32x4*)&u.t.vnb[pr][kk];
            f32x4 u0 = *(const f32x4*)(w1r + kk);
            #pragma unroll
            for (int j = 0; j < 4; ++j) a += u0[j] * vv[j];
        }
        u.t.w1vb[pr][n] = a;
    }

    // ---------------- w2h = h @ W2^T (MFMA, own 16 rows) -------------------------
    f32x4 aw[8];
    #pragma unroll
    for (int nt = 0; nt < 8; ++nt) aw[nt] = f32x4{0.f, 0.f, 0.f, 0.f};
    #pragma unroll
    for (int ks = 0; ks < 4; ++ks) {
        const int kl = ks * 32 + kg * 8;
        s16x8 ah = *(const s16x8*)&u.t.hbuf[pr][fz * 16 + l15][kl];
        #pragma unroll
        for (int nt = 0; nt < 8; ++nt) {
            s16x8 bw = *(const s16x8*)&w2b[(size_t)(nt * 16 + l15) * 128 + kl];
            aw[nt] = MFMA16(ah, bw, aw[nt]);
        }
    }
    __syncthreads();   // B3: w1vb visible

    // ---------------- alpha rows (own 16 rows, wave-local) -----------------------
    float prt[4] = {0.f, 0.f, 0.f, 0.f};
    #pragma unroll
    for (int nt = 0; nt < 8; ++nt) {
        const int n = nt * 16 + l15;
        const float qn = qw[n], wv_ = u.t.w1vb[pr][n], bb = b2[n];
        #pragma unroll
        for (int rj = 0; rj < 4; ++rj)
            prt[rj] += qn * sigm(wv_ + aw[nt][rj] + bb);
    }
    const float qbias = qb[0];
    #pragma unroll
    for (int rj = 0; rj < 4; ++rj) {
        float v = prt[rj];
        v += __shfl_xor(v, 1); v += __shfl_xor(v, 2);
        v += __shfl_xor(v, 4); v += __shfl_xor(v, 8);
        prt[rj] = v + qbias;          // alpha for row fz*16 + kg*4 + rj
    }

    // ---------------- s_g partial over own 16 rows -------------------------------
    #pragma unroll
    for (int nt = 0; nt < 8; ++nt) {
        float sgv = 0.f;
        #pragma unroll
        for (int rj = 0; rj < 4; ++rj) sgv += prt[rj] * hreg[nt][rj];
        sgv += __shfl_xor(sgv, 16);
        sgv += __shfl_xor(sgv, 32);
        if (l < 16) u.t.sglp[pr][fz][nt * 16 + l15] = sgv;
    }
    __syncthreads();   // B4

    // ---------------- out = W3 @ [v_n ; s_g] + b3 --------------------------------
    {
        const int n = fz * 64 + l;
        const float* w3r = W3 + (size_t)n * 256;
        float o = b3[n];
        #pragma unroll
        for (int kk = 0; kk < 128; kk += 4) {
            f32x4 vv = *(const f32x4*)&u.t.vnb[pr][kk];
            f32x4 s0 = *(const f32x4*)&u.t.sglp[pr][0][kk];
            f32x4 s1 = *(const f32x4*)&u.t.sglp[pr][1][kk];
            f32x4 a0 = *(const f32x4*)(w3r + kk);
            f32x4 c0 = *(const f32x4*)(w3r + 128 + kk);
            #pragma unroll
            for (int j = 0; j < 4; ++j)
                o += a0[j] * vv[j] + c0[j] * (s0[j] + s1[j]);
        }
        out[(size_t)sess * 128 + n] = o;
    }
}

// ---- naive fallback (only if ws too small; correctness insurance) ------------
__global__ __launch_bounds__(128) void itemfusing_naive(
    const float* __restrict__ inter, const float* __restrict__ intra,
    const float* __restrict__ Wf1, const float* __restrict__ bf1,
    const float* __restrict__ Wf2, const float* __restrict__ bf2,
    const float* __restrict__ W1,  const float* __restrict__ b1,
    const float* __restrict__ W2,  const float* __restrict__ b2,
    const float* __restrict__ qw,  const float* __restrict__ qb,
    const float* __restrict__ W3,  const float* __restrict__ b3,
    float* __restrict__ out)
{
    __shared__ float h[32][128];
    __shared__ float vn[128], w1v[128], al[32], sg[128], red[128];
    const int n = threadIdx.x; const int sess = blockIdx.x;
    for (int t0 = 0; t0 < 32; ++t0) {
        const float* e1 = inter + (size_t)(sess * 32 + t0) * 1024;
        const float* e2 = intra + (size_t)(sess * 32 + t0) * 1024;
        const float* r1 = Wf1 + (size_t)n * 1024;
        const float* r2 = Wf2 + (size_t)n * 1024;
        float s1 = bf1[n], s2 = bf2[n];
        for (int k = 0; k < 1024; ++k) { s1 += e1[k] * r1[k]; s2 += e2[k] * r2[k]; }
        float g = sigm(s1 + s2);
        h[t0][n] = s2 + g * (s1 - s2);
    }
    __syncthreads();
    vn[n] = h[31][n];
    __syncthreads();
    { float a = b1[n]; const float* w1r = W1 + (size_t)n * 128;
      for (int k = 0; k < 128; ++k) a += w1r[k] * vn[k];
      w1v[n] = a; }
    __syncthreads();
    for (int t0 = 0; t0 < 32; ++t0) {
        float x = b2[n]; const float* w2r = W2 + (size_t)n * 128;
        for (int k = 0; k < 128; ++k) x += w2r[k] * h[t0][k];
        red[n] = qw[n] * sigm(w1v[n] + x); __syncthreads();
        for (int s_ = 64; s_ > 0; s_ >>= 1) { if (n < s_) red[n] += red[n + s_]; __syncthreads(); }
        if (n == 0) al[t0] = red[0] + qb[0];
        __syncthreads();
    }
    { float s = 0.f; for (int t0 = 0; t0 < 32; ++t0) s += al[t0] * h[t0][n];
      sg[n] = s; }
    __syncthreads();
    { float o = b3[n]; const float* w3r = W3 + (size_t)n * 256;
      for (int k = 0; k < 128; ++k) o += w3r[k] * vn[k] + w3r[128 + k] * sg[k];
      out[(size_t)sess * 128 + n] = o; }
}

extern "C" void kernel_launch(void* const* d_in, const int* in_sizes, int n_in,
                              void* d_out, int out_size, void* d_ws, size_t ws_size,
                              hipStream_t stream) {
    (void)n_in; (void)out_size;
    const float* inter = (const float*)d_in[0];
    const float* intra = (const float*)d_in[1];
    const float* Wf1   = (const float*)d_in[3];
    const float* bf1   = (const float*)d_in[4];
    const float* Wf2   = (const float*)d_in[5];
    const float* bf2   = (const float*)d_in[6];
    const float* W1    = (const float*)d_in[7];
    const float* b1    = (const float*)d_in[8];
    const float* W2    = (const float*)d_in[9];
    const float* b2    = (const float*)d_in[10];
    const float* qw    = (const float*)d_in[11];
    const float* qb    = (const float*)d_in[12];
    const float* W3    = (const float*)d_in[13];
    const float* b3    = (const float*)d_in[14];
    float* out = (float*)d_out;

    const int nsess = in_sizes[2];               // 4096
    const size_t WS_NEED = (size_t)(524288 + 16384) * sizeof(short);

    if (d_ws != nullptr && ws_size >= WS_NEED) {
        short* wsp = (short*)d_ws;
        itemfusing_prep<<<264, 256, 0, stream>>>(Wf1, Wf2, W2, wsp);
        itemfusing_main<<<nsess / 2, THREADS, 0, stream>>>(
            inter, intra, bf1, bf2, W1, b1, b2, qw, qb, W3, b3,
            wsp, wsp + 524288, out);
    } else {
        itemfusing_naive<<<nsess, 128, 0, stream>>>(
            inter, intra, Wf1, bf1, Wf2, bf2, W1, b1, W2, b2, qw, qb, W3, b3, out);
    }
}